// Round 5
// baseline (343.131 us; speedup 1.0000x reference)
//
#include <hip/hip_runtime.h>
#include <hip/hip_fp16.h>

// CTC forward loss. B=64, T=2000, C=128 (blank=127), Lmax=200, S=401.
// SINGLE kernel, intra-block producer-consumer, TWO BATCHES PER BLOCK (v5).
// Analysis of v4: consumer round2 = ~65 VALU (~130 cyc issue) but measured
// ~380 cyc -- a single in-order wave can't fill its own dependent-VALU
// latency bubbles (~230 idle issue cyc/round2; MfmaUtil 0, HBM 2.6%).
// v5: 512 threads = 8 waves. Waves 0-3 = batch A {consumer, 3 producers},
// waves 4-7 = batch B. With round-robin wave->SIMD placement (i%4), SIMD0
// hosts BOTH consumer waves: the SIMD scheduler interleaves them, filling
// each wave's stalls with the other's instructions (per-batch round2 cost
// -> ~260 cyc issue-bound instead of 380 bubble-bound). Producers pair on
// SIMDs 1-3 with ~4x slack. All per-batch math, LDS layout, and sync
// structure identical to v4 -> absmax must stay 0.0.
//   consumer (wvl==0): alpha recursion, linear domain + pow2 exponent
//     tracking, DPP halos, 8 states/lane, NAMED prefetch regs.
//   producers (wvl=1..3): pair-granular, branch-free, stage1 (12 row loads
//     to named regs) + stage2 (6 pair computes), ds_write_b128.
// Sync: one __syncthreads() per chunk (block-uniform loop bound kmax);
// per-sub double buffer parity k&1; garbage pairs -> scratch slots 16/17.

#define LOG2E 1.44269504088896340736f
#define LN2F  0.69314718055994530942f

namespace {

constexpr int Bc = 64, Tc = 2000, Cc = 128, Lmaxc = 200;
constexpr int PAIRB = 1024;                  // bytes per pair (64 lanes x 16)
constexpr int CHP = 16;                      // pairs per chunk (32 steps)
constexpr int CHPA = 18;                     // allocated pair slots (2 scratch)
constexpr int CHB = CHPA * PAIRB;            // 18 KB per buffer
constexpr int NSUB = 2;                      // batches per block

__device__ __forceinline__ float dpp_shr1_f(float x) {  // lane i <- i-1, lane0 <- 0
  return __int_as_float(
      __builtin_amdgcn_update_dpp(0, __float_as_int(x), 0x138, 0xF, 0xF, true));
}
__device__ __forceinline__ int dpp_shr1_i(int x) {
  return __builtin_amdgcn_update_dpp(0, x, 0x138, 0xF, 0xF, true);
}
template <int CTRL>
__device__ __forceinline__ float dpp_add(float v) {
  return v + __int_as_float(
      __builtin_amdgcn_update_dpp(0, __float_as_int(v), CTRL, 0xF, 0xF, true));
}
__device__ __forceinline__ float wave_sum_bcast(float v) {  // full-wave sum
  v = dpp_add<0x111>(v);
  v = dpp_add<0x112>(v);
  v = dpp_add<0x114>(v);
  v = dpp_add<0x118>(v);
  v = dpp_add<0x142>(v);
  v = dpp_add<0x143>(v);
  return __int_as_float(__builtin_amdgcn_readlane(__float_as_int(v), 63));
}

__global__ __launch_bounds__(512, 2) void ctc_fused_kernel(
    const float* __restrict__ y, const int* __restrict__ y_true,
    const int* __restrict__ in_len, const int* __restrict__ lab_len,
    float* __restrict__ out) {
  __shared__ __align__(16) char bufs[NSUB][2][CHB];   // 72 KB pair buffers
  __shared__ __align__(16) float blkb[NSUB][2][40];   // blank probs

  const int sub = threadIdx.x >> 8;            // 0: waves 0-3, 1: waves 4-7
  const int wvl = (threadIdx.x >> 6) & 3;      // role within sub-pipeline
  const int lane = threadIdx.x & 63;
  const int lane16 = lane * 16;
  const int b = blockIdx.x * 2 + sub;

  auto clampLen = [](int L) { return L < 1 ? 1 : (L > Tc ? Tc : L); };
  const int lenA = clampLen(in_len[blockIdx.x * 2]);
  const int lenB = clampLen(in_len[blockIdx.x * 2 + 1]);
  const int len = (sub == 0) ? lenA : lenB;
  const int R = (len - 1) >> 1;          // full pair-rounds
  const int leftover = (len - 1) & 1;
  const int PRtot = R + leftover;        // pairs touched
  const int NCg = (PRtot + CHP - 1) / CHP;
  const int cfull = R / CHP;
  const int cfA = ((lenA - 1) >> 1) / CHP;
  const int cfB = ((lenB - 1) >> 1) / CHP;
  const int kmax = cfA > cfB ? cfA : cfB;      // block-uniform loop bound
  const int* labs = y_true + b * Lmaxc;

  // ---- producer-side label classes (pack_kernel's fix() semantics) ----
  int pbase = 4 * lane;
  if (pbase > Lmaxc - 4) pbase = Lmaxc - 4;
  const int4 Lw = *(const int4*)(labs + pbase);
  auto fix = [&](int v, int idx) {
    int r = (idx > Lmaxc - 1) ? Lw.w : v;  // idx>199 -> labs[199]
    return r < 0 ? 0 : r;                  // padded -1 -> 0
  };
  const int c0 = fix(Lw.x, 4 * lane), c1 = fix(Lw.y, 4 * lane + 1);
  const int c2 = fix(Lw.z, 4 * lane + 2), c3 = fix(Lw.w, 4 * lane + 3);
  const float* yrow = y + (size_t)b * Tc * Cc + 2 * lane;

  // softmax+gather from a pre-loaded row -> packed 8B; bl = blank prob
  auto pack2 = [&](float2 yy, float& bl) -> uint2 {
    float e0 = exp2f(fminf(yy.x * LOG2E, 50.f));
    float e1 = exp2f(fminf(yy.y * LOG2E, 50.f));
    const float rs = 1.0f / wave_sum_bcast(e0 + e1);
    unsigned q2 =
        __builtin_bit_cast(unsigned, __floats2half2_rn(e0 * rs, e1 * rs));
    unsigned g0 = (unsigned)__builtin_amdgcn_ds_bpermute((c0 >> 1) << 2, (int)q2);
    unsigned g1 = (unsigned)__builtin_amdgcn_ds_bpermute((c1 >> 1) << 2, (int)q2);
    unsigned g2 = (unsigned)__builtin_amdgcn_ds_bpermute((c2 >> 1) << 2, (int)q2);
    unsigned g3 = (unsigned)__builtin_amdgcn_ds_bpermute((c3 >> 1) << 2, (int)q2);
    unsigned h0 = (c0 & 1) ? (g0 >> 16) : (g0 & 0xFFFFu);
    unsigned h1 = (c1 & 1) ? (g1 >> 16) : (g1 & 0xFFFFu);
    unsigned h2 = (c2 & 1) ? (g2 >> 16) : (g2 & 0xFFFFu);
    unsigned h3 = (c3 & 1) ? (g3 >> 16) : (g3 & 0xFFFFu);
    bl = e1 * rs;  // lane 63 holds class-127 (blank) prob
    return make_uint2(h0 | (h1 << 16), h2 | (h3 << 16));
  };

  // producer: wave wvl packs local pairs wvl-1 + 3i (i<6) of chunk kp.
  // Branch-free: t clamped; garbage pairs land in scratch slots 16/17 or at
  // clamped rows -- never read by the consumer (reads slots 0..15, pairs < R).
  auto produce = [&](int kp) {
    char* pbuf = &bufs[sub][kp & 1][0];
    float* bb = blkb[sub][kp & 1];
    const int pq0 = wvl - 1;             // 0,1,2
    const int tbase = 32 * kp + 1;       // step of slot A of local pair 0
    // ---- stage 1: all 12 row loads in flight (named regs only) ----
    float2 yA0, yB0, yA1, yB1, yA2, yB2, yA3, yB3, yA4, yB4, yA5, yB5;
#define LOADP(i, yA, yB)                                    \
  {                                                         \
    int tA = tbase + 2 * (pq0 + 3 * (i));                   \
    int tB = tA + 1;                                        \
    tA = tA > Tc - 1 ? Tc - 1 : tA;                         \
    tB = tB > Tc - 1 ? Tc - 1 : tB;                         \
    yA = *(const float2*)(yrow + (size_t)tA * Cc);          \
    yB = *(const float2*)(yrow + (size_t)tB * Cc);          \
  }
    LOADP(0, yA0, yB0)
    LOADP(1, yA1, yB1)
    LOADP(2, yA2, yB2)
    LOADP(3, yA3, yB3)
    LOADP(4, yA4, yB4)
    LOADP(5, yA5, yB5)
#undef LOADP
    // ---- stage 2: compute + write 6 pairs, straight-line ----
#define PACKP(i, yA, yB)                                             \
  {                                                                  \
    const int pq = pq0 + 3 * (i);                                    \
    float blA, blB;                                                  \
    const uint2 wA = pack2(yA, blA);                                 \
    const uint2 wB = pack2(yB, blB);                                 \
    *(uint4*)(pbuf + pq * PAIRB + lane16) =                          \
        make_uint4(wA.x, wA.y, wB.x, wB.y);                          \
    if (lane == 63) *(float2*)(bb + 2 * pq) = make_float2(blA, blB); \
  }
    PACKP(0, yA0, yB0)
    PACKP(1, yA1, yB1)
    PACKP(2, yA2, yB2)
    PACKP(3, yA3, yB3)
    PACKP(4, yA4, yB4)
    PACKP(5, yA5, yB5)
#undef PACKP
  };

  // ---- consumer-side per-lane state (wvl==0 wave of each sub uses it) ----
  const int ll = lab_len[b];
  auto labc = [&](int l) -> int {
    int lc = l < 0 ? 0 : (l > Lmaxc - 1 ? Lmaxc - 1 : l);
    int c = labs[lc];
    return c < 0 ? 0 : c;
  };
  const int c0i = labc(4 * lane), c1i = labc(4 * lane + 1);
  const int c2i = labc(4 * lane + 2), c3i = labc(4 * lane + 3);
  const int cm1 = labc(4 * lane - 1), cm2 = labc(4 * lane - 2);
  const float sk0 = (4 * lane >= 1 && c0i != cm1) ? 1.f : 0.f;
  const float sk1 = (c1i != c0i) ? 1.f : 0.f;
  const float sk2 = (c2i != c1i) ? 1.f : 0.f;
  const float sk3 = (c3i != c2i) ? 1.f : 0.f;
  const float skH = (lane >= 1 && cm1 != cm2) ? 1.f : 0.f;

  float a0 = 0.f, a1 = 0.f, a2 = 0.f, a3 = 0.f;
  float a4 = 0.f, a5 = 0.f, a6 = 0.f, a7 = 0.f;
  int E = 0;
  if (wvl == 0) {  // seed from y row t=0 (row 0 is never packed)
    const float* y0 = y + (size_t)b * Tc * Cc + 2 * lane;
    float e0 = exp2f(fminf(y0[0] * LOG2E, 50.f));
    float e1 = exp2f(fminf(y0[1] * LOG2E, 50.f));
    const float rs = 1.0f / wave_sum_bcast(e0 + e1);
    int l0 = labs[0];
    l0 = l0 < 0 ? 0 : l0;
    float ev = (l0 & 1) ? e1 : e0;
    float q0 = __int_as_float(__builtin_amdgcn_readlane(__float_as_int(ev), l0 >> 1)) * rs;
    float qb = __int_as_float(__builtin_amdgcn_readlane(__float_as_int(e1), 63)) * rs;
    if (lane == 0) { a0 = qb; a1 = q0; }
  }
  float s7d = dpp_shr1_f(a7), s6d = dpp_shr1_f(a6), s5d = dpp_shr1_f(a5);
  int epd = 0;
  float corr = (lane == 0) ? 0.f : 1.f;

  // pair-round: 2 lattice steps from one 16B slot + f32 blank pair
  auto round2 = [&](uint4 rw, float2 bl, bool renorm) {
    float2 aLo = __half22float2(*(__half2*)&rw.x);
    float2 aHi = __half22float2(*(__half2*)&rw.y);
    float2 bLo = __half22float2(*(__half2*)&rw.z);
    float2 bHi = __half22float2(*(__half2*)&rw.w);
    const float qbA = bl.x, qbB = bl.y;
    const float qhA = dpp_shr1_f(aHi.y);  // halo label prob (VALU pipe)
    const float w7 = s7d * corr, w6 = s6d * corr, w5 = s5d * corr;
    const float hA = (w7 + w6 + skH * w5) * qhA;
    float n0 = (a0 + w7) * qbA;
    float n1 = (a1 + a0 + sk0 * w7) * aLo.x;
    float n2 = (a2 + a1) * qbA;
    float n3 = (a3 + a2 + sk1 * a1) * aLo.y;
    float n4 = (a4 + a3) * qbA;
    float n5 = (a5 + a4 + sk2 * a3) * aHi.x;
    float n6 = (a6 + a5) * qbA;
    float n7 = (a7 + a6 + sk3 * a5) * aHi.y;
    a0 = (n0 + hA) * qbB;
    a1 = (n1 + n0 + sk0 * hA) * bLo.x;
    a2 = (n2 + n1) * qbB;
    a3 = (n3 + n2 + sk1 * n1) * bLo.y;
    a4 = (n4 + n3) * qbB;
    a5 = (n5 + n4 + sk2 * n3) * bHi.x;
    a6 = (n6 + n5) * qbB;
    a7 = (n7 + n6 + sk3 * n5) * bHi.y;
    if (renorm) {  // every 8 steps, exact pow2
      float mx = fmaxf(fmaxf(fmaxf(a0, a1), fmaxf(a2, a3)),
                       fmaxf(fmaxf(a4, a5), fmaxf(a6, a7)));
      unsigned bits = __float_as_uint(mx);
      bool z = (bits == 0u);
      int e = (int)(bits >> 23) - 127;
      float f = __uint_as_float((254u - (bits >> 23)) << 23);  // 2^-e
      f = z ? 1.0f : f;
      a0 *= f; a1 *= f; a2 *= f; a3 *= f;
      a4 *= f; a5 *= f; a6 *= f; a7 *= f;
      E = z ? epd : (E + e);
    }
    s7d = dpp_shr1_f(a7);
    s6d = dpp_shr1_f(a6);
    s5d = dpp_shr1_f(a5);
    if (renorm) {
      epd = dpp_shr1_i(E);
      int de = epd - E;
      de = de < -126 ? -126 : (de > 60 ? 60 : de);
      corr = __int_as_float((de + 127) << 23);
      corr = (lane == 0) ? 0.0f : corr;
    }
  };

  // consume one full 16-round chunk. NAMED prefetch registers only.
  auto consume = [&](int k) {
    const char* cb = &bufs[sub][k & 1][0];
    const float* pb = blkb[sub][k & 1];
    uint4 rawA = *(const uint4*)(cb + 0 * PAIRB + lane16);
    float2 blA = *(const float2*)(pb + 0);
    uint4 rawB = *(const uint4*)(cb + 1 * PAIRB + lane16);
    float2 blB = *(const float2*)(pb + 2);
#pragma unroll
    for (int h = 0; h < 8; ++h) {
      uint4 ra = rawA;
      float2 ba = blA;
      if (h < 7) {
        rawA = *(const uint4*)(cb + (2 * h + 2) * PAIRB + lane16);
        blA = *(const float2*)(pb + (4 * h + 4));
      }
      round2(ra, ba, false);
      uint4 rb = rawB;
      float2 bb2 = blB;
      if (h < 7) {
        rawB = *(const uint4*)(cb + (2 * h + 3) * PAIRB + lane16);
        blB = *(const float2*)(pb + (4 * h + 6));
      }
      round2(rb, bb2, (h & 1) == 1);
    }
  };

  // ---- pipeline: uniform barriers, producers one chunk ahead ----
  if (wvl != 0 && NCg > 0) produce(0);
  __syncthreads();
  for (int k = 0; k < kmax; ++k) {
    if (wvl == 0) {
      if (k < cfull) consume(k);
    } else if (k + 1 < NCg) {
      produce(k + 1);
    }
    __syncthreads();
  }

  if (wvl != 0) return;  // producers done (no barriers past this point)

  // tail: remaining pair-rounds + optional single step, from tail chunk
  {
    const char* tb = &bufs[sub][cfull & 1][0];
    const float* pbT = blkb[sub][cfull & 1];
    const int rem = R - cfull * CHP;
    for (int r = 0; r < rem; ++r) {
      uint4 rw = *(const uint4*)(tb + r * PAIRB + lane16);
      float2 bl = *(const float2*)(pbT + 2 * r);
      round2(rw, bl, (r & 3) == 3);
    }
    if (leftover) {  // final odd step: slot A of pair R
      uint4 rw = *(const uint4*)(tb + rem * PAIRB + lane16);
      float blA = *(pbT + 2 * rem);
      float2 flo = __half22float2(*(__half2*)&rw.x);
      float2 fhi = __half22float2(*(__half2*)&rw.y);
      float s7 = dpp_shr1_f(a7);
      int ep = dpp_shr1_i(E);
      int de = ep - E;
      de = de < -126 ? -126 : (de > 60 ? 60 : de);
      float c2v = __int_as_float((de + 127) << 23);
      c2v = (lane == 0) ? 0.0f : c2v;
      float w7 = s7 * c2v;
      float n0 = (a0 + w7) * blA;
      float n1 = (a1 + a0 + sk0 * w7) * flo.x;
      float n2 = (a2 + a1) * blA;
      float n3 = (a3 + a2 + sk1 * a1) * flo.y;
      float n4 = (a4 + a3) * blA;
      float n5 = (a5 + a4 + sk2 * a3) * fhi.x;
      float n6 = (a6 + a5) * blA;
      float n7 = (a7 + a6 + sk3 * a5) * fhi.y;
      a0 = n0; a1 = n1; a2 = n2; a3 = n3;
      a4 = n4; a5 = n5; a6 = n6; a7 = n7;
    }
  }

  // final combine: loss = -lse(alpha[2ll], alpha[2ll-1]) in log2 domain
  int sE = 2 * ll;
  int sP = sE - 1 < 0 ? 0 : sE - 1;
  int laneA = sE >> 3, jA = sE & 7;
  int laneB = sP >> 3, jB = sP & 7;
  float va = a0;
  if (jA == 1) va = a1;
  if (jA == 2) va = a2;
  if (jA == 3) va = a3;
  if (jA == 4) va = a4;
  if (jA == 5) va = a5;
  if (jA == 6) va = a6;
  if (jA == 7) va = a7;
  float vb = a0;
  if (jB == 1) vb = a1;
  if (jB == 2) vb = a2;
  if (jB == 3) vb = a3;
  if (jB == 4) vb = a4;
  if (jB == 5) vb = a5;
  if (jB == 6) vb = a6;
  if (jB == 7) vb = a7;
  float aA = __int_as_float(__builtin_amdgcn_ds_bpermute(laneA << 2, __float_as_int(va)));
  float aB = __int_as_float(__builtin_amdgcn_ds_bpermute(laneB << 2, __float_as_int(vb)));
  int EA = __builtin_amdgcn_ds_bpermute(laneA << 2, E);
  int EB = __builtin_amdgcn_ds_bpermute(laneB << 2, E);
  if (lane == 0) {
    float l1 = (aA > 0.0f) ? (float)EA + log2f(aA) : -1e30f;
    float l2 = (aB > 0.0f) ? (float)EB + log2f(aB) : -1e30f;
    float mm = fmaxf(l1, l2);
    float v = mm + log2f(exp2f(l1 - mm) + exp2f(l2 - mm));
    out[b] = -v * LN2F;
  }
}

}  // namespace

extern "C" void kernel_launch(void* const* d_in, const int* in_sizes, int n_in,
                              void* d_out, int out_size, void* d_ws, size_t ws_size,
                              hipStream_t stream) {
  const float* y = (const float*)d_in[0];   // [64,2000,128] f32
  const int* yt = (const int*)d_in[1];      // [64,200] i32
  const int* il = (const int*)d_in[2];      // [64] i32
  const int* lb = (const int*)d_in[3];      // [64] i32
  float* out = (float*)d_out;               // [64] f32
  (void)d_ws; (void)ws_size;                // no workspace needed

  hipLaunchKernelGGL(ctc_fused_kernel, dim3(Bc / 2), dim3(512), 0, stream,
                     y, yt, il, lb, out);
}

// Round 6
// 234.873 us; speedup vs baseline: 1.4609x; 1.4609x over previous
//
#include <hip/hip_runtime.h>
#include <hip/hip_fp16.h>

// CTC forward loss. B=64, T=2000, C=128 (blank=127), Lmax=200, S=401.
// SINGLE kernel, intra-block producer-consumer. One block per batch (256 thr)
// -- REVERT of the failed v5 2-batch/block experiment (halving CUs needed a
// 2x SMT overlap that measured only 1.19x). Structure = proven v4 (157.7us):
//   wave 0      : alpha recursion (linear domain + pow2 exponent tracking,
//                 DPP halos, 8 states/lane, NAMED prefetch regs).
//   waves 1..3  : producers, pair-granular, branch-free, stage1 (12 row
//                 loads -> named regs) + stage2 (6 pair computes).
// v6 change: LDS pair storage is F32, not half (v4 spent 8 v_cvt_f32_f16 of
// the ~69-instr serial round2 unpacking half2 -- 12% of the consumer's
// issue stream plus cvt->use latency). Pair = 2 contiguous 1KB step-quads;
// lane's 4 probs = 16B -> ds_read_b128 stride-16, conflict-free (same proven
// pattern). Producer gathers E0/E1 with 2 bpermutes + cndmask per class
// (+4 ds ops/row, producer has ~2x slack). Probs are no longer rounded to
// half -> strictly closer to the reference than the passing v4.
// Sync: one __syncthreads() per chunk; double buffer parity k&1; garbage
// pairs -> scratch slots 16/17 or clamped rows, never read by the consumer.

#define LOG2E 1.44269504088896340736f
#define LN2F  0.69314718055994530942f

namespace {

constexpr int Bc = 64, Tc = 2000, Cc = 128, Lmaxc = 200;
constexpr int PAIRB = 2048;                  // bytes per pair (2 x 1KB quads)
constexpr int CHP = 16;                      // pairs per chunk (32 steps)
constexpr int CHPA = 18;                     // allocated pair slots (2 scratch)
constexpr int CHB = CHPA * PAIRB;            // 36 KB per buffer

__device__ __forceinline__ float dpp_shr1_f(float x) {  // lane i <- i-1, lane0 <- 0
  return __int_as_float(
      __builtin_amdgcn_update_dpp(0, __float_as_int(x), 0x138, 0xF, 0xF, true));
}
__device__ __forceinline__ int dpp_shr1_i(int x) {
  return __builtin_amdgcn_update_dpp(0, x, 0x138, 0xF, 0xF, true);
}
template <int CTRL>
__device__ __forceinline__ float dpp_add(float v) {
  return v + __int_as_float(
      __builtin_amdgcn_update_dpp(0, __float_as_int(v), CTRL, 0xF, 0xF, true));
}
__device__ __forceinline__ float wave_sum_bcast(float v) {  // full-wave sum
  v = dpp_add<0x111>(v);
  v = dpp_add<0x112>(v);
  v = dpp_add<0x114>(v);
  v = dpp_add<0x118>(v);
  v = dpp_add<0x142>(v);
  v = dpp_add<0x143>(v);
  return __int_as_float(__builtin_amdgcn_readlane(__float_as_int(v), 63));
}

__global__ __launch_bounds__(256, 1) void ctc_fused_kernel(
    const float* __restrict__ y, const int* __restrict__ y_true,
    const int* __restrict__ in_len, const int* __restrict__ lab_len,
    float* __restrict__ out) {
  __shared__ __align__(16) char bufs[2][CHB];   // 72 KB pair double buffer
  __shared__ __align__(16) float blkb[2][40];   // blank probs (+scratch tail)

  const int b = blockIdx.x;
  const int wv = threadIdx.x >> 6, lane = threadIdx.x & 63;
  const int lane16 = lane * 16;

  int len = in_len[b];
  len = len < 1 ? 1 : (len > Tc ? Tc : len);
  const int R = (len - 1) >> 1;          // full pair-rounds
  const int leftover = (len - 1) & 1;
  const int PRtot = R + leftover;        // pairs touched
  const int NCg = (PRtot + CHP - 1) / CHP;
  const int cfull = R / CHP;
  const int* labs = y_true + b * Lmaxc;

  // ---- producer-side label classes (pack_kernel's fix() semantics) ----
  int pbase = 4 * lane;
  if (pbase > Lmaxc - 4) pbase = Lmaxc - 4;
  const int4 Lw = *(const int4*)(labs + pbase);
  auto fix = [&](int v, int idx) {
    int r = (idx > Lmaxc - 1) ? Lw.w : v;  // idx>199 -> labs[199]
    return r < 0 ? 0 : r;                  // padded -1 -> 0
  };
  const int c0 = fix(Lw.x, 4 * lane), c1 = fix(Lw.y, 4 * lane + 1);
  const int c2 = fix(Lw.z, 4 * lane + 2), c3 = fix(Lw.w, 4 * lane + 3);
  const float* yrow = y + (size_t)b * Tc * Cc + 2 * lane;

  // softmax+gather from a pre-loaded row -> 4 f32 label probs; bl = blank
  auto pack2f = [&](float2 yy, float& bl) -> uint4 {
    float e0 = exp2f(fminf(yy.x * LOG2E, 50.f));
    float e1 = exp2f(fminf(yy.y * LOG2E, 50.f));
    const float rs = 1.0f / wave_sum_bcast(e0 + e1);
    const int E0 = __float_as_int(e0 * rs);
    const int E1 = __float_as_int(e1 * rs);
    int b00 = __builtin_amdgcn_ds_bpermute((c0 >> 1) << 2, E0);
    int b01 = __builtin_amdgcn_ds_bpermute((c0 >> 1) << 2, E1);
    int b10 = __builtin_amdgcn_ds_bpermute((c1 >> 1) << 2, E0);
    int b11 = __builtin_amdgcn_ds_bpermute((c1 >> 1) << 2, E1);
    int b20 = __builtin_amdgcn_ds_bpermute((c2 >> 1) << 2, E0);
    int b21 = __builtin_amdgcn_ds_bpermute((c2 >> 1) << 2, E1);
    int b30 = __builtin_amdgcn_ds_bpermute((c3 >> 1) << 2, E0);
    int b31 = __builtin_amdgcn_ds_bpermute((c3 >> 1) << 2, E1);
    unsigned f0 = (unsigned)((c0 & 1) ? b01 : b00);
    unsigned f1 = (unsigned)((c1 & 1) ? b11 : b10);
    unsigned f2 = (unsigned)((c2 & 1) ? b21 : b20);
    unsigned f3 = (unsigned)((c3 & 1) ? b31 : b30);
    bl = __int_as_float(E1);  // lane 63 holds class-127 (blank) prob
    return make_uint4(f0, f1, f2, f3);
  };

  // producer: wave wv packs local pairs wv-1 + 3i (i<6) of chunk kp.
  // Branch-free: t clamped; garbage pairs land in scratch slots 16/17 or at
  // clamped rows -- never read by the consumer (reads slots 0..15, pairs < R).
  auto produce = [&](int kp) {
    char* pbuf = &bufs[kp & 1][0];
    float* bb = blkb[kp & 1];
    const int pq0 = wv - 1;              // 0,1,2
    const int tbase = 32 * kp + 1;       // step of slot A of local pair 0
    // ---- stage 1: all 12 row loads in flight (named regs only) ----
    float2 yA0, yB0, yA1, yB1, yA2, yB2, yA3, yB3, yA4, yB4, yA5, yB5;
#define LOADP(i, yA, yB)                                    \
  {                                                         \
    int tA = tbase + 2 * (pq0 + 3 * (i));                   \
    int tB = tA + 1;                                        \
    tA = tA > Tc - 1 ? Tc - 1 : tA;                         \
    tB = tB > Tc - 1 ? Tc - 1 : tB;                         \
    yA = *(const float2*)(yrow + (size_t)tA * Cc);          \
    yB = *(const float2*)(yrow + (size_t)tB * Cc);          \
  }
    LOADP(0, yA0, yB0)
    LOADP(1, yA1, yB1)
    LOADP(2, yA2, yB2)
    LOADP(3, yA3, yB3)
    LOADP(4, yA4, yB4)
    LOADP(5, yA5, yB5)
#undef LOADP
    // ---- stage 2: compute + write 6 pairs, straight-line ----
#define PACKP(i, yA, yB)                                             \
  {                                                                  \
    const int pq = pq0 + 3 * (i);                                    \
    float blA, blB;                                                  \
    const uint4 wA = pack2f(yA, blA);                                \
    const uint4 wB = pack2f(yB, blB);                                \
    *(uint4*)(pbuf + pq * PAIRB + lane16) = wA;                      \
    *(uint4*)(pbuf + pq * PAIRB + 1024 + lane16) = wB;               \
    if (lane == 63) *(float2*)(bb + 2 * pq) = make_float2(blA, blB); \
  }
    PACKP(0, yA0, yB0)
    PACKP(1, yA1, yB1)
    PACKP(2, yA2, yB2)
    PACKP(3, yA3, yB3)
    PACKP(4, yA4, yB4)
    PACKP(5, yA5, yB5)
#undef PACKP
  };

  // ---- consumer-side per-lane state (wave 0 only uses it) ----
  const int ll = lab_len[b];
  auto labc = [&](int l) -> int {
    int lc = l < 0 ? 0 : (l > Lmaxc - 1 ? Lmaxc - 1 : l);
    int c = labs[lc];
    return c < 0 ? 0 : c;
  };
  const int c0i = labc(4 * lane), c1i = labc(4 * lane + 1);
  const int c2i = labc(4 * lane + 2), c3i = labc(4 * lane + 3);
  const int cm1 = labc(4 * lane - 1), cm2 = labc(4 * lane - 2);
  const float sk0 = (4 * lane >= 1 && c0i != cm1) ? 1.f : 0.f;
  const float sk1 = (c1i != c0i) ? 1.f : 0.f;
  const float sk2 = (c2i != c1i) ? 1.f : 0.f;
  const float sk3 = (c3i != c2i) ? 1.f : 0.f;
  const float skH = (lane >= 1 && cm1 != cm2) ? 1.f : 0.f;

  float a0 = 0.f, a1 = 0.f, a2 = 0.f, a3 = 0.f;
  float a4 = 0.f, a5 = 0.f, a6 = 0.f, a7 = 0.f;
  int E = 0;
  if (wv == 0) {  // seed from y row t=0 (row 0 is never packed)
    const float* y0 = y + (size_t)b * Tc * Cc + 2 * lane;
    float e0 = exp2f(fminf(y0[0] * LOG2E, 50.f));
    float e1 = exp2f(fminf(y0[1] * LOG2E, 50.f));
    const float rs = 1.0f / wave_sum_bcast(e0 + e1);
    int l0 = labs[0];
    l0 = l0 < 0 ? 0 : l0;
    float ev = (l0 & 1) ? e1 : e0;
    float q0 = __int_as_float(__builtin_amdgcn_readlane(__float_as_int(ev), l0 >> 1)) * rs;
    float qb = __int_as_float(__builtin_amdgcn_readlane(__float_as_int(e1), 63)) * rs;
    if (lane == 0) { a0 = qb; a1 = q0; }
  }
  float s7d = dpp_shr1_f(a7), s6d = dpp_shr1_f(a6), s5d = dpp_shr1_f(a5);
  int epd = 0;
  float corr = (lane == 0) ? 0.f : 1.f;

  // pair-round: 2 lattice steps from two f32 quads + f32 blank pair
  auto round2 = [&](uint4 qa, uint4 qb, float2 bl, bool renorm) {
    const float pA0 = __uint_as_float(qa.x), pA1 = __uint_as_float(qa.y);
    const float pA2 = __uint_as_float(qa.z), pA3 = __uint_as_float(qa.w);
    const float pB0 = __uint_as_float(qb.x), pB1 = __uint_as_float(qb.y);
    const float pB2 = __uint_as_float(qb.z), pB3 = __uint_as_float(qb.w);
    const float qbA = bl.x, qbB = bl.y;
    const float qhA = dpp_shr1_f(pA3);    // halo label prob (VALU pipe)
    const float w7 = s7d * corr, w6 = s6d * corr, w5 = s5d * corr;
    const float hA = (w7 + w6 + skH * w5) * qhA;
    float n0 = (a0 + w7) * qbA;
    float n1 = (a1 + a0 + sk0 * w7) * pA0;
    float n2 = (a2 + a1) * qbA;
    float n3 = (a3 + a2 + sk1 * a1) * pA1;
    float n4 = (a4 + a3) * qbA;
    float n5 = (a5 + a4 + sk2 * a3) * pA2;
    float n6 = (a6 + a5) * qbA;
    float n7 = (a7 + a6 + sk3 * a5) * pA3;
    a0 = (n0 + hA) * qbB;
    a1 = (n1 + n0 + sk0 * hA) * pB0;
    a2 = (n2 + n1) * qbB;
    a3 = (n3 + n2 + sk1 * n1) * pB1;
    a4 = (n4 + n3) * qbB;
    a5 = (n5 + n4 + sk2 * n3) * pB2;
    a6 = (n6 + n5) * qbB;
    a7 = (n7 + n6 + sk3 * n5) * pB3;
    if (renorm) {  // every 8 steps, exact pow2
      float mx = fmaxf(fmaxf(fmaxf(a0, a1), fmaxf(a2, a3)),
                       fmaxf(fmaxf(a4, a5), fmaxf(a6, a7)));
      unsigned bits = __float_as_uint(mx);
      bool z = (bits == 0u);
      int e = (int)(bits >> 23) - 127;
      float f = __uint_as_float((254u - (bits >> 23)) << 23);  // 2^-e
      f = z ? 1.0f : f;
      a0 *= f; a1 *= f; a2 *= f; a3 *= f;
      a4 *= f; a5 *= f; a6 *= f; a7 *= f;
      E = z ? epd : (E + e);
    }
    s7d = dpp_shr1_f(a7);
    s6d = dpp_shr1_f(a6);
    s5d = dpp_shr1_f(a5);
    if (renorm) {
      epd = dpp_shr1_i(E);
      int de = epd - E;
      de = de < -126 ? -126 : (de > 60 ? 60 : de);
      corr = __int_as_float((de + 127) << 23);
      corr = (lane == 0) ? 0.0f : corr;
    }
  };

  // consume one full 16-round chunk. NAMED prefetch registers only.
  auto consume = [&](int k) {
    const char* cb = &bufs[k & 1][0];
    const float* pb = blkb[k & 1];
    uint4 rAa = *(const uint4*)(cb + 0 * PAIRB + lane16);
    uint4 rAb = *(const uint4*)(cb + 0 * PAIRB + 1024 + lane16);
    float2 blA = *(const float2*)(pb + 0);
    uint4 rBa = *(const uint4*)(cb + 1 * PAIRB + lane16);
    uint4 rBb = *(const uint4*)(cb + 1 * PAIRB + 1024 + lane16);
    float2 blB = *(const float2*)(pb + 2);
#pragma unroll
    for (int h = 0; h < 8; ++h) {
      uint4 qa = rAa, qb2 = rAb;
      float2 ba = blA;
      if (h < 7) {
        rAa = *(const uint4*)(cb + (2 * h + 2) * PAIRB + lane16);
        rAb = *(const uint4*)(cb + (2 * h + 2) * PAIRB + 1024 + lane16);
        blA = *(const float2*)(pb + (4 * h + 4));
      }
      round2(qa, qb2, ba, false);
      uint4 qc = rBa, qd = rBb;
      float2 bb2 = blB;
      if (h < 7) {
        rBa = *(const uint4*)(cb + (2 * h + 3) * PAIRB + lane16);
        rBb = *(const uint4*)(cb + (2 * h + 3) * PAIRB + 1024 + lane16);
        blB = *(const float2*)(pb + (4 * h + 6));
      }
      round2(qc, qd, bb2, (h & 1) == 1);
    }
  };

  // ---- pipeline: uniform barriers, producers one chunk ahead ----
  if (wv != 0 && NCg > 0) produce(0);
  __syncthreads();
  for (int k = 0; k < cfull; ++k) {
    if (wv == 0) {
      consume(k);
    } else if (k + 1 < NCg) {
      produce(k + 1);
    }
    __syncthreads();
  }

  if (wv != 0) return;  // producers done (no barriers past this point)

  // tail: remaining pair-rounds + optional single step, from tail chunk
  {
    const char* tb = &bufs[cfull & 1][0];
    const float* pbT = blkb[cfull & 1];
    const int rem = R - cfull * CHP;
    for (int r = 0; r < rem; ++r) {
      uint4 qa = *(const uint4*)(tb + r * PAIRB + lane16);
      uint4 qb2 = *(const uint4*)(tb + r * PAIRB + 1024 + lane16);
      float2 bl = *(const float2*)(pbT + 2 * r);
      round2(qa, qb2, bl, (r & 3) == 3);
    }
    if (leftover) {  // final odd step: slot A of pair R
      uint4 qa = *(const uint4*)(tb + rem * PAIRB + lane16);
      float blA = *(pbT + 2 * rem);
      const float pA0 = __uint_as_float(qa.x), pA1 = __uint_as_float(qa.y);
      const float pA2 = __uint_as_float(qa.z), pA3 = __uint_as_float(qa.w);
      float s7 = dpp_shr1_f(a7);
      int ep = dpp_shr1_i(E);
      int de = ep - E;
      de = de < -126 ? -126 : (de > 60 ? 60 : de);
      float c2v = __int_as_float((de + 127) << 23);
      c2v = (lane == 0) ? 0.0f : c2v;
      float w7 = s7 * c2v;
      float n0 = (a0 + w7) * blA;
      float n1 = (a1 + a0 + sk0 * w7) * pA0;
      float n2 = (a2 + a1) * blA;
      float n3 = (a3 + a2 + sk1 * a1) * pA1;
      float n4 = (a4 + a3) * blA;
      float n5 = (a5 + a4 + sk2 * a3) * pA2;
      float n6 = (a6 + a5) * blA;
      float n7 = (a7 + a6 + sk3 * a5) * pA3;
      a0 = n0; a1 = n1; a2 = n2; a3 = n3;
      a4 = n4; a5 = n5; a6 = n6; a7 = n7;
    }
  }

  // final combine: loss = -lse(alpha[2ll], alpha[2ll-1]) in log2 domain
  int sE = 2 * ll;
  int sP = sE - 1 < 0 ? 0 : sE - 1;
  int laneA = sE >> 3, jA = sE & 7;
  int laneB = sP >> 3, jB = sP & 7;
  float va = a0;
  if (jA == 1) va = a1;
  if (jA == 2) va = a2;
  if (jA == 3) va = a3;
  if (jA == 4) va = a4;
  if (jA == 5) va = a5;
  if (jA == 6) va = a6;
  if (jA == 7) va = a7;
  float vb = a0;
  if (jB == 1) vb = a1;
  if (jB == 2) vb = a2;
  if (jB == 3) vb = a3;
  if (jB == 4) vb = a4;
  if (jB == 5) vb = a5;
  if (jB == 6) vb = a6;
  if (jB == 7) vb = a7;
  float aA = __int_as_float(__builtin_amdgcn_ds_bpermute(laneA << 2, __float_as_int(va)));
  float aB = __int_as_float(__builtin_amdgcn_ds_bpermute(laneB << 2, __float_as_int(vb)));
  int EA = __builtin_amdgcn_ds_bpermute(laneA << 2, E);
  int EB = __builtin_amdgcn_ds_bpermute(laneB << 2, E);
  if (lane == 0) {
    float l1 = (aA > 0.0f) ? (float)EA + log2f(aA) : -1e30f;
    float l2 = (aB > 0.0f) ? (float)EB + log2f(aB) : -1e30f;
    float mm = fmaxf(l1, l2);
    float v = mm + log2f(exp2f(l1 - mm) + exp2f(l2 - mm));
    out[b] = -v * LN2F;
  }
}

}  // namespace

extern "C" void kernel_launch(void* const* d_in, const int* in_sizes, int n_in,
                              void* d_out, int out_size, void* d_ws, size_t ws_size,
                              hipStream_t stream) {
  const float* y = (const float*)d_in[0];   // [64,2000,128] f32
  const int* yt = (const int*)d_in[1];      // [64,200] i32
  const int* il = (const int*)d_in[2];      // [64] i32
  const int* lb = (const int*)d_in[3];      // [64] i32
  float* out = (float*)d_out;               // [64] f32
  (void)d_ws; (void)ws_size;                // no workspace needed

  hipLaunchKernelGGL(ctc_fused_kernel, dim3(Bc), dim3(256), 0, stream,
                     y, yt, il, lb, out);
}

// Round 7
// 224.396 us; speedup vs baseline: 1.5291x; 1.0467x over previous
//
#include <hip/hip_runtime.h>
#include <hip/hip_fp16.h>

// CTC forward loss. B=64, T=2000, C=128 (blank=127), Lmax=200, S=401.
// SINGLE kernel, intra-block producer-consumer. One block per batch (256 thr).
// v7 = v6's f32-quad consumer + v4's 4-bpermute producer:
//   v6 A/B decomposition: consumer {-8 v_cvt_f32_f16, +1 ds_read_b128} was a
//   win, but producer bpermutes doubled 4->8/row (bank conflicts 753K->1.82M)
//   and taxed the shared per-CU LDS pipe more than the cvt savings. v7 keeps
//   the f32 consumer and moves the half->f32 conversion INTO the producer
//   (4 cvts/row, producer has ~2x slack), restoring the 4-bpermute gather.
//   Numerics bit-identical to proven v4 (half->f32 exact).
// Consumer halo refactor: hA = (w7 + corr*(s6d + skH*s5d))*qhA is computed as
//   fmaf(corr, zsd, w7)*qhA with z = fmaf(skH_next, a5, a6) shifted by ONE dpp
//   (skH_next = skH from lane+1, hoisted to init). -3 instr/round2, identical
//   algebra (zsd_i = a6_{i-1} + skH_i * a5_{i-1} = s6d + skH*s5d).
//   wave 0      : alpha recursion (linear domain + pow2 exponent tracking,
//                 DPP halos, 8 states/lane, NAMED prefetch regs).
//   waves 1..3  : producers, pair-granular, branch-free, stage1 (12 row
//                 loads -> named regs) + stage2 (6 pair computes).
// Sync: one __syncthreads() per chunk; double buffer parity k&1; garbage
// pairs -> scratch slots 16/17 or clamped rows, never read by the consumer.

#define LOG2E 1.44269504088896340736f
#define LN2F  0.69314718055994530942f

namespace {

constexpr int Bc = 64, Tc = 2000, Cc = 128, Lmaxc = 200;
constexpr int PAIRB = 2048;                  // bytes per pair (2 x 1KB quads)
constexpr int CHP = 16;                      // pairs per chunk (32 steps)
constexpr int CHPA = 18;                     // allocated pair slots (2 scratch)
constexpr int CHB = CHPA * PAIRB;            // 36 KB per buffer

__device__ __forceinline__ float dpp_shr1_f(float x) {  // lane i <- i-1, lane0 <- 0
  return __int_as_float(
      __builtin_amdgcn_update_dpp(0, __float_as_int(x), 0x138, 0xF, 0xF, true));
}
__device__ __forceinline__ float dpp_shl1_f(float x) {  // lane i <- i+1, lane63 <- 0
  return __int_as_float(
      __builtin_amdgcn_update_dpp(0, __float_as_int(x), 0x130, 0xF, 0xF, true));
}
__device__ __forceinline__ int dpp_shr1_i(int x) {
  return __builtin_amdgcn_update_dpp(0, x, 0x138, 0xF, 0xF, true);
}
template <int CTRL>
__device__ __forceinline__ float dpp_add(float v) {
  return v + __int_as_float(
      __builtin_amdgcn_update_dpp(0, __float_as_int(v), CTRL, 0xF, 0xF, true));
}
__device__ __forceinline__ float wave_sum_bcast(float v) {  // full-wave sum
  v = dpp_add<0x111>(v);
  v = dpp_add<0x112>(v);
  v = dpp_add<0x114>(v);
  v = dpp_add<0x118>(v);
  v = dpp_add<0x142>(v);
  v = dpp_add<0x143>(v);
  return __int_as_float(__builtin_amdgcn_readlane(__float_as_int(v), 63));
}
__device__ __forceinline__ float h16_to_f32(unsigned h) {
  __half_raw hr;
  hr.x = (unsigned short)h;
  return __half2float(__half(hr));
}

__global__ __launch_bounds__(256, 1) void ctc_fused_kernel(
    const float* __restrict__ y, const int* __restrict__ y_true,
    const int* __restrict__ in_len, const int* __restrict__ lab_len,
    float* __restrict__ out) {
  __shared__ __align__(16) char bufs[2][CHB];   // 72 KB pair double buffer
  __shared__ __align__(16) float blkb[2][40];   // blank probs (+scratch tail)

  const int b = blockIdx.x;
  const int wv = threadIdx.x >> 6, lane = threadIdx.x & 63;
  const int lane16 = lane * 16;

  int len = in_len[b];
  len = len < 1 ? 1 : (len > Tc ? Tc : len);
  const int R = (len - 1) >> 1;          // full pair-rounds
  const int leftover = (len - 1) & 1;
  const int PRtot = R + leftover;        // pairs touched
  const int NCg = (PRtot + CHP - 1) / CHP;
  const int cfull = R / CHP;
  const int* labs = y_true + b * Lmaxc;

  // ---- producer-side label classes (pack_kernel's fix() semantics) ----
  int pbase = 4 * lane;
  if (pbase > Lmaxc - 4) pbase = Lmaxc - 4;
  const int4 Lw = *(const int4*)(labs + pbase);
  auto fix = [&](int v, int idx) {
    int r = (idx > Lmaxc - 1) ? Lw.w : v;  // idx>199 -> labs[199]
    return r < 0 ? 0 : r;                  // padded -1 -> 0
  };
  const int c0 = fix(Lw.x, 4 * lane), c1 = fix(Lw.y, 4 * lane + 1);
  const int c2 = fix(Lw.z, 4 * lane + 2), c3 = fix(Lw.w, 4 * lane + 3);
  const float* yrow = y + (size_t)b * Tc * Cc + 2 * lane;

  // softmax + half2-gather (4 bpermutes, proven v4 path) -> 4 f32 label probs
  // (half-rounded then exactly widened => numerics identical to v4).
  auto pack2f = [&](float2 yy, float& bl) -> uint4 {
    float e0 = exp2f(fminf(yy.x * LOG2E, 50.f));
    float e1 = exp2f(fminf(yy.y * LOG2E, 50.f));
    const float rs = 1.0f / wave_sum_bcast(e0 + e1);
    unsigned q2 =
        __builtin_bit_cast(unsigned, __floats2half2_rn(e0 * rs, e1 * rs));
    unsigned g0 = (unsigned)__builtin_amdgcn_ds_bpermute((c0 >> 1) << 2, (int)q2);
    unsigned g1 = (unsigned)__builtin_amdgcn_ds_bpermute((c1 >> 1) << 2, (int)q2);
    unsigned g2 = (unsigned)__builtin_amdgcn_ds_bpermute((c2 >> 1) << 2, (int)q2);
    unsigned g3 = (unsigned)__builtin_amdgcn_ds_bpermute((c3 >> 1) << 2, (int)q2);
    unsigned h0 = (c0 & 1) ? (g0 >> 16) : (g0 & 0xFFFFu);
    unsigned h1 = (c1 & 1) ? (g1 >> 16) : (g1 & 0xFFFFu);
    unsigned h2 = (c2 & 1) ? (g2 >> 16) : (g2 & 0xFFFFu);
    unsigned h3 = (c3 & 1) ? (g3 >> 16) : (g3 & 0xFFFFu);
    bl = e1 * rs;  // lane 63 holds class-127 (blank) prob
    return make_uint4(__builtin_bit_cast(unsigned, h16_to_f32(h0)),
                      __builtin_bit_cast(unsigned, h16_to_f32(h1)),
                      __builtin_bit_cast(unsigned, h16_to_f32(h2)),
                      __builtin_bit_cast(unsigned, h16_to_f32(h3)));
  };

  // producer: wave wv packs local pairs wv-1 + 3i (i<6) of chunk kp.
  // Branch-free: t clamped; garbage pairs land in scratch slots 16/17 or at
  // clamped rows -- never read by the consumer (reads slots 0..15, pairs < R).
  auto produce = [&](int kp) {
    char* pbuf = &bufs[kp & 1][0];
    float* bb = blkb[kp & 1];
    const int pq0 = wv - 1;              // 0,1,2
    const int tbase = 32 * kp + 1;       // step of slot A of local pair 0
    // ---- stage 1: all 12 row loads in flight (named regs only) ----
    float2 yA0, yB0, yA1, yB1, yA2, yB2, yA3, yB3, yA4, yB4, yA5, yB5;
#define LOADP(i, yA, yB)                                    \
  {                                                         \
    int tA = tbase + 2 * (pq0 + 3 * (i));                   \
    int tB = tA + 1;                                        \
    tA = tA > Tc - 1 ? Tc - 1 : tA;                         \
    tB = tB > Tc - 1 ? Tc - 1 : tB;                         \
    yA = *(const float2*)(yrow + (size_t)tA * Cc);          \
    yB = *(const float2*)(yrow + (size_t)tB * Cc);          \
  }
    LOADP(0, yA0, yB0)
    LOADP(1, yA1, yB1)
    LOADP(2, yA2, yB2)
    LOADP(3, yA3, yB3)
    LOADP(4, yA4, yB4)
    LOADP(5, yA5, yB5)
#undef LOADP
    // ---- stage 2: compute + write 6 pairs, straight-line ----
#define PACKP(i, yA, yB)                                             \
  {                                                                  \
    const int pq = pq0 + 3 * (i);                                    \
    float blA, blB;                                                  \
    const uint4 wA = pack2f(yA, blA);                                \
    const uint4 wB = pack2f(yB, blB);                                \
    *(uint4*)(pbuf + pq * PAIRB + lane16) = wA;                      \
    *(uint4*)(pbuf + pq * PAIRB + 1024 + lane16) = wB;               \
    if (lane == 63) *(float2*)(bb + 2 * pq) = make_float2(blA, blB); \
  }
    PACKP(0, yA0, yB0)
    PACKP(1, yA1, yB1)
    PACKP(2, yA2, yB2)
    PACKP(3, yA3, yB3)
    PACKP(4, yA4, yB4)
    PACKP(5, yA5, yB5)
#undef PACKP
  };

  // ---- consumer-side per-lane state (wave 0 only uses it) ----
  const int ll = lab_len[b];
  auto labc = [&](int l) -> int {
    int lc = l < 0 ? 0 : (l > Lmaxc - 1 ? Lmaxc - 1 : l);
    int c = labs[lc];
    return c < 0 ? 0 : c;
  };
  const int c0i = labc(4 * lane), c1i = labc(4 * lane + 1);
  const int c2i = labc(4 * lane + 2), c3i = labc(4 * lane + 3);
  const int cm1 = labc(4 * lane - 1), cm2 = labc(4 * lane - 2);
  const float sk0 = (4 * lane >= 1 && c0i != cm1) ? 1.f : 0.f;
  const float sk1 = (c1i != c0i) ? 1.f : 0.f;
  const float sk2 = (c2i != c1i) ? 1.f : 0.f;
  const float sk3 = (c3i != c2i) ? 1.f : 0.f;
  const float skH = (lane >= 1 && cm1 != cm2) ? 1.f : 0.f;
  const float skHn = dpp_shl1_f(skH);  // skH of lane+1 (const, hoisted)

  float a0 = 0.f, a1 = 0.f, a2 = 0.f, a3 = 0.f;
  float a4 = 0.f, a5 = 0.f, a6 = 0.f, a7 = 0.f;
  int E = 0;
  if (wv == 0) {  // seed from y row t=0 (row 0 is never packed)
    const float* y0 = y + (size_t)b * Tc * Cc + 2 * lane;
    float e0 = exp2f(fminf(y0[0] * LOG2E, 50.f));
    float e1 = exp2f(fminf(y0[1] * LOG2E, 50.f));
    const float rs = 1.0f / wave_sum_bcast(e0 + e1);
    int l0 = labs[0];
    l0 = l0 < 0 ? 0 : l0;
    float ev = (l0 & 1) ? e1 : e0;
    float q0 = __int_as_float(__builtin_amdgcn_readlane(__float_as_int(ev), l0 >> 1)) * rs;
    float qb = __int_as_float(__builtin_amdgcn_readlane(__float_as_int(e1), 63)) * rs;
    if (lane == 0) { a0 = qb; a1 = q0; }
  }
  float s7d = dpp_shr1_f(a7);
  float zsd = dpp_shr1_f(fmaf(skHn, a5, a6));  // s6d + skH*s5d, one dpp
  int epd = 0;
  float corr = (lane == 0) ? 0.f : 1.f;

  // pair-round: 2 lattice steps from two f32 quads + f32 blank pair
  auto round2 = [&](uint4 qa, uint4 qb, float2 bl, bool renorm) {
    const float pA0 = __uint_as_float(qa.x), pA1 = __uint_as_float(qa.y);
    const float pA2 = __uint_as_float(qa.z), pA3 = __uint_as_float(qa.w);
    const float pB0 = __uint_as_float(qb.x), pB1 = __uint_as_float(qb.y);
    const float pB2 = __uint_as_float(qb.z), pB3 = __uint_as_float(qb.w);
    const float qbA = bl.x, qbB = bl.y;
    const float qhA = dpp_shr1_f(pA3);    // halo label prob (VALU pipe)
    const float w7 = s7d * corr;
    const float hA = fmaf(corr, zsd, w7) * qhA;  // == (w7+w6+skH*w5)*qhA
    float n0 = (a0 + w7) * qbA;
    float n1 = (a1 + a0 + sk0 * w7) * pA0;
    float n2 = (a2 + a1) * qbA;
    float n3 = (a3 + a2 + sk1 * a1) * pA1;
    float n4 = (a4 + a3) * qbA;
    float n5 = (a5 + a4 + sk2 * a3) * pA2;
    float n6 = (a6 + a5) * qbA;
    float n7 = (a7 + a6 + sk3 * a5) * pA3;
    a0 = (n0 + hA) * qbB;
    a1 = (n1 + n0 + sk0 * hA) * pB0;
    a2 = (n2 + n1) * qbB;
    a3 = (n3 + n2 + sk1 * n1) * pB1;
    a4 = (n4 + n3) * qbB;
    a5 = (n5 + n4 + sk2 * n3) * pB2;
    a6 = (n6 + n5) * qbB;
    a7 = (n7 + n6 + sk3 * n5) * pB3;
    if (renorm) {  // every 8 steps, exact pow2
      float mx = fmaxf(fmaxf(fmaxf(a0, a1), fmaxf(a2, a3)),
                       fmaxf(fmaxf(a4, a5), fmaxf(a6, a7)));
      unsigned bits = __float_as_uint(mx);
      bool z = (bits == 0u);
      int e = (int)(bits >> 23) - 127;
      float f = __uint_as_float((254u - (bits >> 23)) << 23);  // 2^-e
      f = z ? 1.0f : f;
      a0 *= f; a1 *= f; a2 *= f; a3 *= f;
      a4 *= f; a5 *= f; a6 *= f; a7 *= f;
      E = z ? epd : (E + e);
    }
    s7d = dpp_shr1_f(a7);
    zsd = dpp_shr1_f(fmaf(skHn, a5, a6));
    if (renorm) {
      epd = dpp_shr1_i(E);
      int de = epd - E;
      de = de < -126 ? -126 : (de > 60 ? 60 : de);
      corr = __int_as_float((de + 127) << 23);
      corr = (lane == 0) ? 0.0f : corr;
    }
  };

  // consume one full 16-round chunk. NAMED prefetch registers only.
  auto consume = [&](int k) {
    const char* cb = &bufs[k & 1][0];
    const float* pb = blkb[k & 1];
    uint4 rAa = *(const uint4*)(cb + 0 * PAIRB + lane16);
    uint4 rAb = *(const uint4*)(cb + 0 * PAIRB + 1024 + lane16);
    float2 blA = *(const float2*)(pb + 0);
    uint4 rBa = *(const uint4*)(cb + 1 * PAIRB + lane16);
    uint4 rBb = *(const uint4*)(cb + 1 * PAIRB + 1024 + lane16);
    float2 blB = *(const float2*)(pb + 2);
#pragma unroll
    for (int h = 0; h < 8; ++h) {
      uint4 qa = rAa, qb2 = rAb;
      float2 ba = blA;
      if (h < 7) {
        rAa = *(const uint4*)(cb + (2 * h + 2) * PAIRB + lane16);
        rAb = *(const uint4*)(cb + (2 * h + 2) * PAIRB + 1024 + lane16);
        blA = *(const float2*)(pb + (4 * h + 4));
      }
      round2(qa, qb2, ba, false);
      uint4 qc = rBa, qd = rBb;
      float2 bb2 = blB;
      if (h < 7) {
        rBa = *(const uint4*)(cb + (2 * h + 3) * PAIRB + lane16);
        rBb = *(const uint4*)(cb + (2 * h + 3) * PAIRB + 1024 + lane16);
        blB = *(const float2*)(pb + (4 * h + 6));
      }
      round2(qc, qd, bb2, (h & 1) == 1);
    }
  };

  // ---- pipeline: uniform barriers, producers one chunk ahead ----
  if (wv != 0 && NCg > 0) produce(0);
  __syncthreads();
  for (int k = 0; k < cfull; ++k) {
    if (wv == 0) {
      consume(k);
    } else if (k + 1 < NCg) {
      produce(k + 1);
    }
    __syncthreads();
  }

  if (wv != 0) return;  // producers done (no barriers past this point)

  // tail: remaining pair-rounds + optional single step, from tail chunk
  {
    const char* tb = &bufs[cfull & 1][0];
    const float* pbT = blkb[cfull & 1];
    const int rem = R - cfull * CHP;
    for (int r = 0; r < rem; ++r) {
      uint4 qa = *(const uint4*)(tb + r * PAIRB + lane16);
      uint4 qb2 = *(const uint4*)(tb + r * PAIRB + 1024 + lane16);
      float2 bl = *(const float2*)(pbT + 2 * r);
      round2(qa, qb2, bl, (r & 3) == 3);
    }
    if (leftover) {  // final odd step: slot A of pair R
      uint4 qa = *(const uint4*)(tb + rem * PAIRB + lane16);
      float blA = *(pbT + 2 * rem);
      const float pA0 = __uint_as_float(qa.x), pA1 = __uint_as_float(qa.y);
      const float pA2 = __uint_as_float(qa.z), pA3 = __uint_as_float(qa.w);
      float s7 = dpp_shr1_f(a7);
      int ep = dpp_shr1_i(E);
      int de = ep - E;
      de = de < -126 ? -126 : (de > 60 ? 60 : de);
      float c2v = __int_as_float((de + 127) << 23);
      c2v = (lane == 0) ? 0.0f : c2v;
      float w7 = s7 * c2v;
      float n0 = (a0 + w7) * blA;
      float n1 = (a1 + a0 + sk0 * w7) * pA0;
      float n2 = (a2 + a1) * blA;
      float n3 = (a3 + a2 + sk1 * a1) * pA1;
      float n4 = (a4 + a3) * blA;
      float n5 = (a5 + a4 + sk2 * a3) * pA2;
      float n6 = (a6 + a5) * blA;
      float n7 = (a7 + a6 + sk3 * a5) * pA3;
      a0 = n0; a1 = n1; a2 = n2; a3 = n3;
      a4 = n4; a5 = n5; a6 = n6; a7 = n7;
    }
  }

  // final combine: loss = -lse(alpha[2ll], alpha[2ll-1]) in log2 domain
  int sE = 2 * ll;
  int sP = sE - 1 < 0 ? 0 : sE - 1;
  int laneA = sE >> 3, jA = sE & 7;
  int laneB = sP >> 3, jB = sP & 7;
  float va = a0;
  if (jA == 1) va = a1;
  if (jA == 2) va = a2;
  if (jA == 3) va = a3;
  if (jA == 4) va = a4;
  if (jA == 5) va = a5;
  if (jA == 6) va = a6;
  if (jA == 7) va = a7;
  float vb = a0;
  if (jB == 1) vb = a1;
  if (jB == 2) vb = a2;
  if (jB == 3) vb = a3;
  if (jB == 4) vb = a4;
  if (jB == 5) vb = a5;
  if (jB == 6) vb = a6;
  if (jB == 7) vb = a7;
  float aA = __int_as_float(__builtin_amdgcn_ds_bpermute(laneA << 2, __float_as_int(va)));
  float aB = __int_as_float(__builtin_amdgcn_ds_bpermute(laneB << 2, __float_as_int(vb)));
  int EA = __builtin_amdgcn_ds_bpermute(laneA << 2, E);
  int EB = __builtin_amdgcn_ds_bpermute(laneB << 2, E);
  if (lane == 0) {
    float l1 = (aA > 0.0f) ? (float)EA + log2f(aA) : -1e30f;
    float l2 = (aB > 0.0f) ? (float)EB + log2f(aB) : -1e30f;
    float mm = fmaxf(l1, l2);
    float v = mm + log2f(exp2f(l1 - mm) + exp2f(l2 - mm));
    out[b] = -v * LN2F;
  }
}

}  // namespace

extern "C" void kernel_launch(void* const* d_in, const int* in_sizes, int n_in,
                              void* d_out, int out_size, void* d_ws, size_t ws_size,
                              hipStream_t stream) {
  const float* y = (const float*)d_in[0];   // [64,2000,128] f32
  const int* yt = (const int*)d_in[1];      // [64,200] i32
  const int* il = (const int*)d_in[2];      // [64] i32
  const int* lb = (const int*)d_in[3];      // [64] i32
  float* out = (float*)d_out;               // [64] f32
  (void)d_ws; (void)ws_size;                // no workspace needed

  hipLaunchKernelGGL(ctc_fused_kernel, dim3(Bc), dim3(256), 0, stream,
                     y, yt, il, lb, out);
}